// Round 4
// baseline (833.091 us; speedup 1.0000x reference)
//
#include <hip/hip_runtime.h>
#include <math.h>

typedef unsigned short ushort_t;
typedef unsigned int uint_t;

#define NPTS 65536
#define NSAMP 16
#define CH 64
#define NROWS (NPTS*NSAMP)
#define BN_EPS 1e-5f

// workspace layout (float offsets)
#define OFF_S3   0            // sum3[3], sq3[3]
#define OFF_F3   8            // scale3[3], shift3[3]
#define OFF_S64  16           // sum64[64] @16, sq64[64] @80
#define OFF_F64  144          // scale64[64] @144, shift64[64] @208
#define OFF_S8   272          // sum8[8], sq8[8]
#define OFF_F8   288          // scale8[8], shift8[8]
#define OFF_XQ   512
#define OFF_XKH  (OFF_XQ + NPTS*CH)            // bf16 xk: NPTS*CH ushorts
#define OFF_XVH  (OFF_XKH + NPTS*CH/2)         // bf16 xv
#define OFF_PR1  (OFF_XVH + NPTS*CH/2)
#define OFF_W2   (OFF_PR1 + (size_t)NROWS*3)

__device__ __forceinline__ float wave_sum(float v){
#pragma unroll
  for (int m = 32; m > 0; m >>= 1) v += __shfl_xor(v, m);
  return v;
}

__device__ __forceinline__ ushort_t f2bf(float f){
  uint_t u = __float_as_uint(f);
  u += 0x7fffu + ((u >> 16) & 1u);   // round-to-nearest-even
  return (ushort_t)(u >> 16);
}
__device__ __forceinline__ float bf2f(ushort_t h){
  return __uint_as_float(((uint_t)h) << 16);
}

__global__ void k_zero(float* __restrict__ ws){
  if (threadIdx.x < 512) ws[threadIdx.x] = 0.0f;
}

// q/k/v projections: thread per point; y=0 -> xq fp32, y=1 -> xk bf16, y=2 -> xv bf16
__global__ __launch_bounds__(256) void k_proj(const float* __restrict__ x,
    const float* __restrict__ W0, const float* __restrict__ b0,
    const float* __restrict__ W1, const float* __restrict__ b1,
    const float* __restrict__ W2, const float* __restrict__ b2,
    float* __restrict__ xqo, ushort_t* __restrict__ xkh, ushort_t* __restrict__ xvh)
{
  int n = blockIdx.x * blockDim.x + threadIdx.x;
  const float* W; const float* b;
  if (blockIdx.y == 0)      { W = W0; b = b0; }
  else if (blockIdx.y == 1) { W = W1; b = b1; }
  else                      { W = W2; b = b2; }

  float4 xr[16];
  const float4* xp = (const float4*)(x + (size_t)n * CH);
#pragma unroll
  for (int i = 0; i < 16; i++) xr[i] = xp[i];

  float4* opf = (float4*)(xqo + (size_t)n * CH);
  ushort_t* oph = ((blockIdx.y == 1) ? xkh : xvh) + (size_t)n * CH;

#pragma unroll 1
  for (int o4 = 0; o4 < 16; o4++){
    float a[4];
#pragma unroll
    for (int oo = 0; oo < 4; oo++){
      int o = o4 * 4 + oo;
      float acc = b[o];
      const float4* wp = (const float4*)(W + o * CH);
#pragma unroll
      for (int i = 0; i < 16; i++){
        float4 w4 = wp[i];
        acc += xr[i].x * w4.x + xr[i].y * w4.y + xr[i].z * w4.z + xr[i].w * w4.w;
      }
      a[oo] = acc;
    }
    if (blockIdx.y == 0){
      float4 st; st.x = a[0]; st.y = a[1]; st.z = a[2]; st.w = a[3];
      opf[o4] = st;
    } else {
      uint2 st;
      st.x = (uint_t)f2bf(a[0]) | ((uint_t)f2bf(a[1]) << 16);
      st.y = (uint_t)f2bf(a[2]) | ((uint_t)f2bf(a[3]) << 16);
      ((uint2*)oph)[o4] = st;
    }
  }
}

// p_r stage 1 (Linear(3,3)) + BN3 partial sums. 4 rows/thread, full ILP.
__global__ __launch_bounds__(256) void k_pr1(const float* __restrict__ p,
    const int* __restrict__ idx, const float* __restrict__ Wp1,
    const float* __restrict__ bp1, float* __restrict__ ws)
{
  float* pr1 = ws + OFF_PR1;
  float w00=Wp1[0],w01=Wp1[1],w02=Wp1[2];
  float w10=Wp1[3],w11=Wp1[4],w12=Wp1[5];
  float w20=Wp1[6],w21=Wp1[7],w22=Wp1[8];
  float b0=bp1[0],b1=bp1[1],b2=bp1[2];
  float s0=0,s1=0,s2=0,q0=0,q1=0,q2=0;
  int r0 = blockIdx.x*256 + threadIdx.x;
#pragma unroll
  for (int it = 0; it < 4; it++){
    int r = r0 + it*262144;
    int n = r >> 4;
    int iv = idx[r];
    float dx = p[iv*3+0] - p[n*3+0];
    float dy = p[iv*3+1] - p[n*3+1];
    float dz = p[iv*3+2] - p[n*3+2];
    float v0 = b0 + dx*w00 + dy*w01 + dz*w02;
    float v1 = b1 + dx*w10 + dy*w11 + dz*w12;
    float v2 = b2 + dx*w20 + dy*w21 + dz*w22;
    pr1[(size_t)r*3+0]=v0; pr1[(size_t)r*3+1]=v1; pr1[(size_t)r*3+2]=v2;
    s0+=v0; s1+=v1; s2+=v2;
    q0+=v0*v0; q1+=v1*v1; q2+=v2*v2;
  }
  s0=wave_sum(s0); s1=wave_sum(s1); s2=wave_sum(s2);
  q0=wave_sum(q0); q1=wave_sum(q1); q2=wave_sum(q2);
  __shared__ float lds[4][6];
  int lane = threadIdx.x & 63, wv = threadIdx.x >> 6;
  if (lane == 0){
    lds[wv][0]=s0; lds[wv][1]=s1; lds[wv][2]=s2;
    lds[wv][3]=q0; lds[wv][4]=q1; lds[wv][5]=q2;
  }
  __syncthreads();
  if (threadIdx.x < 6){
    float v = lds[0][threadIdx.x]+lds[1][threadIdx.x]+lds[2][threadIdx.x]+lds[3][threadIdx.x];
    atomicAdd(ws + OFF_S3 + threadIdx.x, v);
  }
}

// BN finalize: scale = g*rsqrt(var+eps), shift = beta - mean*scale
__global__ void k_finalize(const float* __restrict__ sums, float* __restrict__ outf,
                           const float* __restrict__ g, const float* __restrict__ beta, int nch)
{
  int t = threadIdx.x;
  if (t < nch){
    float invM = 1.0f / (float)NROWS;
    float mean = sums[t] * invM;
    float var  = sums[nch + t] * invM - mean * mean;
    float rs   = rsqrtf(var + BN_EPS);
    float sc   = g[t] * rs;
    outf[t] = sc;
    outf[nch + t] = beta[t] - mean * sc;
  }
}

// BN64 stats over w_pre = xk[idx] - xq + p_r2.
// Wave per 64 rows, lane = channel. Per-row scalars via UNIFORM loads
// (row index is wave-uniform -> no shfl); 8 gathers in flight per group.
__global__ __launch_bounds__(256) void k_stats64(const int* __restrict__ idx,
    const float* __restrict__ xq, const ushort_t* __restrict__ xkh,
    const float* __restrict__ pr1, const float* __restrict__ f3,
    const float* __restrict__ Wp2, const float* __restrict__ bp2,
    float* __restrict__ s64)
{
  int lane = threadIdx.x & 63, wv = threadIdx.x >> 6;
  int row0 = __builtin_amdgcn_readfirstlane((blockIdx.x*4 + wv) * 64);
  int n0 = row0 >> 4;

  float sc0=f3[0], sc1=f3[1], sc2=f3[2], sh0=f3[3], sh1=f3[4], sh2=f3[5];
  float wpa = Wp2[lane*3+0], wpb = Wp2[lane*3+1], wpc = Wp2[lane*3+2];
  float bp  = bp2[lane];

  float xqv[4];
#pragma unroll
  for (int j = 0; j < 4; j++) xqv[j] = xq[(size_t)(n0+j)*CH + lane];

  float accs = 0.0f, accq = 0.0f;
#pragma unroll
  for (int g = 0; g < 8; g++){
    int iv[8]; float a0[8], a1[8], a2[8];
#pragma unroll
    for (int u = 0; u < 8; u++){
      int r = row0 + g*8 + u;               // wave-uniform
      iv[u] = idx[r];
      a0[u] = pr1[(size_t)r*3+0];
      a1[u] = pr1[(size_t)r*3+1];
      a2[u] = pr1[(size_t)r*3+2];
    }
    ushort_t xkv[8];
#pragma unroll
    for (int u = 0; u < 8; u++) xkv[u] = xkh[(size_t)iv[u]*CH + lane];
    float xqcur = xqv[g >> 1];
#pragma unroll
    for (int u = 0; u < 8; u++){
      float rb0 = fmaxf(fmaf(a0[u], sc0, sh0), 0.0f);
      float rb1 = fmaxf(fmaf(a1[u], sc1, sh1), 0.0f);
      float rb2 = fmaxf(fmaf(a2[u], sc2, sh2), 0.0f);
      float pr2v = bp + rb0*wpa + rb1*wpb + rb2*wpc;
      float w = bf2f(xkv[u]) - xqcur + pr2v;
      accs += w; accq = fmaf(w, w, accq);
    }
  }
  __shared__ float lds[4][128];
  lds[wv][lane] = accs; lds[wv][64+lane] = accq;
  __syncthreads();
  if (threadIdx.x < 128){
    float v = lds[0][threadIdx.x]+lds[1][threadIdx.x]+lds[2][threadIdx.x]+lds[3][threadIdx.x];
    atomicAdd(s64 + threadIdx.x, v);
  }
}

// w2 = relu(bn64(w_pre)) @ Ww1^T + bw1 + BN8 partial sums.
// Wave-synchronous, wave owns 64 rows. Per 8-row group:
//   phase A (lane=channel): uniform scalars + 8 gathers -> rb -> LDS strip
//   phase B (lane=(u,o)): 64-FMA dot, Ww1 via L1 broadcast loads
// LDS strips double-buffered; no shfl anywhere in the loop.
__global__ __launch_bounds__(256) void k_w2(const int* __restrict__ idx,
    const float* __restrict__ xq, const ushort_t* __restrict__ xkh,
    const float* __restrict__ pr1, const float* __restrict__ f3,
    const float* __restrict__ f64, const float* __restrict__ Wp2,
    const float* __restrict__ bp2, const float* __restrict__ Ww1,
    const float* __restrict__ bw1, float* __restrict__ w2o,
    float* __restrict__ s8out)
{
  __shared__ __align__(16) float lds[4][2][8][68];
  __shared__ float scr[4][16];
  int lane = threadIdx.x & 63, wv = threadIdx.x >> 6;
  int o = lane & 7, u = lane >> 3;
  int row0 = __builtin_amdgcn_readfirstlane((blockIdx.x*4 + wv) * 64);
  int n0 = row0 >> 4;

  float sc30=f3[0], sc31=f3[1], sc32=f3[2], sh30=f3[3], sh31=f3[4], sh32=f3[5];
  float wpa = Wp2[lane*3+0], wpb = Wp2[lane*3+1], wpc = Wp2[lane*3+2];
  float bp  = bp2[lane];
  float bsc = f64[lane], bsh = f64[64+lane];
  float bb = bw1[o];
  const float* Wrow = Ww1 + o*CH;

  float xqv[4];
#pragma unroll
  for (int j = 0; j < 4; j++) xqv[j] = xq[(size_t)(n0+j)*CH + lane];

  float ssum = 0.0f, qsum = 0.0f;

#pragma unroll
  for (int g = 0; g < 8; g++){
    int iv[8]; float a0[8], a1[8], a2[8];
#pragma unroll
    for (int t = 0; t < 8; t++){
      int r = row0 + g*8 + t;               // wave-uniform
      iv[t] = idx[r];
      a0[t] = pr1[(size_t)r*3+0];
      a1[t] = pr1[(size_t)r*3+1];
      a2[t] = pr1[(size_t)r*3+2];
    }
    ushort_t xkv[8];
#pragma unroll
    for (int t = 0; t < 8; t++) xkv[t] = xkh[(size_t)iv[t]*CH + lane];
    float xqcur = xqv[g >> 1];
    // phase A: rb for 8 rows, lane = channel
#pragma unroll
    for (int t = 0; t < 8; t++){
      float rb0 = fmaxf(fmaf(a0[t], sc30, sh30), 0.0f);
      float rb1 = fmaxf(fmaf(a1[t], sc31, sh31), 0.0f);
      float rb2 = fmaxf(fmaf(a2[t], sc32, sh32), 0.0f);
      float pr2v = bp + rb0*wpa + rb1*wpb + rb2*wpc;
      float w = bf2f(xkv[t]) - xqcur + pr2v;
      lds[wv][g & 1][t][lane] = fmaxf(fmaf(w, bsc, bsh), 0.0f);
    }
    // phase B: same wave, lane = (u,o); ds_write->ds_read ordered by lgkmcnt
    float acc = bb;
#pragma unroll
    for (int c4 = 0; c4 < 16; c4++){
      float4 rv = *(const float4*)(&lds[wv][g & 1][u][c4*4]);
      float4 w4 = *(const float4*)(Wrow + c4*4);
      acc += rv.x*w4.x + rv.y*w4.y + rv.z*w4.z + rv.w*w4.w;
    }
    w2o[(size_t)row0*8 + g*64 + lane] = acc;   // == (row0+g*8+u)*8 + o
    ssum += acc; qsum = fmaf(acc, acc, qsum);
  }

  // per-o reduction: sum over u (lane bits 3..5)
#pragma unroll
  for (int m = 8; m <= 32; m <<= 1){
    ssum += __shfl_xor(ssum, m);
    qsum += __shfl_xor(qsum, m);
  }
  if (lane < 8){ scr[wv][lane] = ssum; scr[wv][8+lane] = qsum; }
  __syncthreads();
  if (threadIdx.x < 16){
    float v = scr[0][threadIdx.x]+scr[1][threadIdx.x]+scr[2][threadIdx.x]+scr[3][threadIdx.x];
    atomicAdd(s8out + threadIdx.x, v);
  }
}

// final: w3 = relu(bn8(w2)) @ Ww2^T + bw2 ; softmax over 16 neighbors ;
// out = sum_j (xv+p_r2)*w. Per-row scalars via uniform loads; all 16 bf16
// xv gathers issued before the softmax math.
__global__ __launch_bounds__(256) void k_out(const int* __restrict__ idx,
    const ushort_t* __restrict__ xvh, const float* __restrict__ pr1,
    const float* __restrict__ w2, const float* __restrict__ f3,
    const float* __restrict__ f8, const float* __restrict__ Wp2,
    const float* __restrict__ bp2, const float* __restrict__ Ww2,
    const float* __restrict__ bw2, float* __restrict__ out)
{
  int lane = threadIdx.x & 63, wv = threadIdx.x >> 6;
  int n = __builtin_amdgcn_readfirstlane(blockIdx.x*4 + wv);
  int cp = lane & 7;
  int jg = lane >> 3;

  // uniform per-row scalars for the point's 16 rows (L1: ~8 lines total)
  int iv[16]; float a0[16], a1[16], a2[16];
#pragma unroll
  for (int j = 0; j < 16; j++){
    int r = n*NSAMP + j;                    // wave-uniform
    iv[j] = idx[r];
    a0[j] = pr1[(size_t)r*3+0];
    a1[j] = pr1[(size_t)r*3+1];
    a2[j] = pr1[(size_t)r*3+2];
  }
  // issue all 16 xv row-gathers up front
  ushort_t xvv[16];
#pragma unroll
  for (int j = 0; j < 16; j++) xvv[j] = xvh[(size_t)iv[j]*CH + lane];

  float wpa = Wp2[lane*3+0], wpb = Wp2[lane*3+1], wpc = Wp2[lane*3+2];
  float bp  = bp2[lane];
  float ww2_[8];
#pragma unroll
  for (int k = 0; k < 8; k++) ww2_[k] = Ww2[cp*8 + k];
  float bw = bw2[cp];
  float sc8[8], sh8[8];
#pragma unroll
  for (int k = 0; k < 8; k++){ sc8[k]=f8[k]; sh8[k]=f8[8+k]; }
  float sc30=f3[0], sc31=f3[1], sc32=f3[2], sh30=f3[3], sh31=f3[4], sh32=f3[5];

  // phase 1: w3 for (jg, cp) and (jg+8, cp)
  const float4* ra  = (const float4*)(w2 + ((size_t)n*NSAMP + jg)*8);
  const float4* rbp = (const float4*)(w2 + ((size_t)n*NSAMP + jg + 8)*8);
  float4 A0 = ra[0],  A1 = ra[1];
  float4 B0 = rbp[0], B1 = rbp[1];
  float w3a = bw, w3b = bw;
#pragma unroll
  for (int k = 0; k < 8; k++){
    float va = (k < 4) ? ((k==0)?A0.x:(k==1)?A0.y:(k==2)?A0.z:A0.w)
                       : ((k==4)?A1.x:(k==5)?A1.y:(k==6)?A1.z:A1.w);
    float vb = (k < 4) ? ((k==0)?B0.x:(k==1)?B0.y:(k==2)?B0.z:B0.w)
                       : ((k==4)?B1.x:(k==5)?B1.y:(k==6)?B1.z:B1.w);
    float rba = fmaxf(va*sc8[k]+sh8[k], 0.0f);
    float rbb = fmaxf(vb*sc8[k]+sh8[k], 0.0f);
    w3a += rba * ww2_[k];
    w3b += rbb * ww2_[k];
  }

  // softmax over 16 neighbors (values for fixed cp live at lanes stride-8)
  float m = fmaxf(w3a, w3b);
#pragma unroll
  for (int mask = 8; mask <= 32; mask <<= 1) m = fmaxf(m, __shfl_xor(m, mask));
  float ea = expf(w3a - m), eb = expf(w3b - m);
  float ssum = ea + eb;
#pragma unroll
  for (int mask = 8; mask <= 32; mask <<= 1) ssum += __shfl_xor(ssum, mask);
  float inv = 1.0f / ssum;
  ea *= inv; eb *= inv;

  // phase 2: accumulate out[n, lane]
  float oacc = 0.0f;
#pragma unroll
  for (int j = 0; j < NSAMP; j++){
    float wn = __shfl(j < 8 ? ea : eb, ((j & 7) << 3) | cp);
    float rb0 = fmaxf(fmaf(a0[j], sc30, sh30), 0.0f);
    float rb1 = fmaxf(fmaf(a1[j], sc31, sh31), 0.0f);
    float rb2 = fmaxf(fmaf(a2[j], sc32, sh32), 0.0f);
    float pr2v = bp + rb0*wpa + rb1*wpb + rb2*wpc;
    oacc += (bf2f(xvv[j]) + pr2v) * wn;
  }
  out[(size_t)n*CH + lane] = oacc;
}

extern "C" void kernel_launch(void* const* d_in, const int* in_sizes, int n_in,
                              void* d_out, int out_size, void* d_ws, size_t ws_size,
                              hipStream_t stream)
{
  const float* p    = (const float*)d_in[0];
  const float* x    = (const float*)d_in[1];
  const int*   idx  = (const int*)d_in[2];
  const float* Wq   = (const float*)d_in[3];
  const float* bq   = (const float*)d_in[4];
  const float* Wk   = (const float*)d_in[5];
  const float* bk   = (const float*)d_in[6];
  const float* Wv   = (const float*)d_in[7];
  const float* bv   = (const float*)d_in[8];
  const float* Wp1  = (const float*)d_in[9];
  const float* bp1  = (const float*)d_in[10];
  const float* gp   = (const float*)d_in[11];
  const float* betap= (const float*)d_in[12];
  const float* Wp2  = (const float*)d_in[13];
  const float* bp2  = (const float*)d_in[14];
  const float* gw1  = (const float*)d_in[15];
  const float* betaw1=(const float*)d_in[16];
  const float* Ww1  = (const float*)d_in[17];
  const float* bw1  = (const float*)d_in[18];
  const float* gw2  = (const float*)d_in[19];
  const float* betaw2=(const float*)d_in[20];
  const float* Ww2  = (const float*)d_in[21];
  const float* bw2  = (const float*)d_in[22];
  float* ws  = (float*)d_ws;
  float* out = (float*)d_out;

  float*    xq  = ws + OFF_XQ;
  ushort_t* xkh = (ushort_t*)(ws + OFF_XKH);
  ushort_t* xvh = (ushort_t*)(ws + OFF_XVH);

  k_zero<<<dim3(1), dim3(512), 0, stream>>>(ws);
  k_proj<<<dim3(NPTS/256, 3), dim3(256), 0, stream>>>(x, Wq,bq, Wk,bk, Wv,bv,
      xq, xkh, xvh);
  k_pr1<<<dim3(1024), dim3(256), 0, stream>>>(p, idx, Wp1, bp1, ws);
  k_finalize<<<dim3(1), dim3(64), 0, stream>>>(ws+OFF_S3, ws+OFF_F3, gp, betap, 3);
  k_stats64<<<dim3(4096), dim3(256), 0, stream>>>(idx, xq, xkh,
      ws+OFF_PR1, ws+OFF_F3, Wp2, bp2, ws+OFF_S64);
  k_finalize<<<dim3(1), dim3(64), 0, stream>>>(ws+OFF_S64, ws+OFF_F64, gw1, betaw1, 64);
  k_w2<<<dim3(4096), dim3(256), 0, stream>>>(idx, xq, xkh, ws+OFF_PR1,
      ws+OFF_F3, ws+OFF_F64, Wp2, bp2, Ww1, bw1, ws+OFF_W2, ws+OFF_S8);
  k_finalize<<<dim3(1), dim3(64), 0, stream>>>(ws+OFF_S8, ws+OFF_F8, gw2, betaw2, 8);
  k_out<<<dim3(NPTS/4), dim3(256), 0, stream>>>(idx, xvh, ws+OFF_PR1, ws+OFF_W2,
      ws+OFF_F3, ws+OFF_F8, Wp2, bp2, Ww2, bw2, out);
}

// Round 7
// 431.901 us; speedup vs baseline: 1.9289x; 1.9289x over previous
//
#include <hip/hip_runtime.h>
#include <math.h>

typedef unsigned short ushort_t;
typedef unsigned int uint_t;
typedef __attribute__((ext_vector_type(8))) short bf16x8;
typedef __attribute__((ext_vector_type(4))) float f32x4;

#define NPTS 65536
#define NSAMP 16
#define CH 64
#define NROWS (NPTS*NSAMP)
#define NTILES (NROWS/16)
#define BN_EPS 1e-5f

// stat banks: 8 banks x 160 floats
#define BANKS 8
#define BANK_STRIDE 160
#define BOFF_S3S 0     // sum3[3] @0, sq3[3] @3
#define BOFF_S64S 16   // sum64[64] @16
#define BOFF_S64Q 80   // sq64[64] @80
#define BOFF_S8S 144   // sum8[8]
#define BOFF_S8Q 152   // sq8[8]
// finalized scale/shift
#define OFF_F3   1536  // scale3[3], shift3[3]
#define OFF_F64  1544  // scale64[64], shift64[64]
#define OFF_F8   1672  // scale8[8], shift8[8]
// big arrays (float offsets)
#define OFF_XQH  2048
#define OFF_XKH  (OFF_XQH + NPTS*CH/2)
#define OFF_XVH  (OFF_XKH + NPTS*CH/2)
#define OFF_PR1  (OFF_XVH + NPTS*CH/2)
#define OFF_W2   (OFF_PR1 + (size_t)NROWS*3)
// total ~17.8M floats ~71MB

__device__ __forceinline__ float wave_sum(float v){
#pragma unroll
  for (int m = 32; m > 0; m >>= 1) v += __shfl_xor(v, m);
  return v;
}
__device__ __forceinline__ ushort_t f2bf(float f){
  uint_t u = __float_as_uint(f);
  u += 0x7fffu + ((u >> 16) & 1u);
  return (ushort_t)(u >> 16);
}
__device__ __forceinline__ float bf2f(ushort_t h){
  return __uint_as_float(((uint_t)h) << 16);
}

__global__ void k_zero(float* __restrict__ ws){
  for (int i = threadIdx.x; i < 2048; i += 256) ws[i] = 0.0f;
}

// q/k/v projections -> bf16 outputs
__global__ __launch_bounds__(256) void k_proj(const float* __restrict__ x,
    const float* __restrict__ W0, const float* __restrict__ b0,
    const float* __restrict__ W1, const float* __restrict__ b1,
    const float* __restrict__ W2, const float* __restrict__ b2,
    ushort_t* __restrict__ xqh, ushort_t* __restrict__ xkh, ushort_t* __restrict__ xvh)
{
  int n = blockIdx.x * blockDim.x + threadIdx.x;
  const float* W; const float* b; ushort_t* outp;
  if (blockIdx.y == 0)      { W = W0; b = b0; outp = xqh; }
  else if (blockIdx.y == 1) { W = W1; b = b1; outp = xkh; }
  else                      { W = W2; b = b2; outp = xvh; }

  float4 xr[16];
  const float4* xp = (const float4*)(x + (size_t)n * CH);
#pragma unroll
  for (int i = 0; i < 16; i++) xr[i] = xp[i];

  ushort_t* oph = outp + (size_t)n * CH;
#pragma unroll 1
  for (int o4 = 0; o4 < 16; o4++){
    float a[4];
#pragma unroll
    for (int oo = 0; oo < 4; oo++){
      int o = o4 * 4 + oo;
      float acc = b[o];
      const float4* wp = (const float4*)(W + o * CH);
#pragma unroll
      for (int i = 0; i < 16; i++){
        float4 w4 = wp[i];
        acc += xr[i].x * w4.x + xr[i].y * w4.y + xr[i].z * w4.z + xr[i].w * w4.w;
      }
      a[oo] = acc;
    }
    uint2 st;
    st.x = (uint_t)f2bf(a[0]) | ((uint_t)f2bf(a[1]) << 16);
    st.y = (uint_t)f2bf(a[2]) | ((uint_t)f2bf(a[3]) << 16);
    ((uint2*)oph)[o4] = st;
  }
}

// p_r stage 1 (Linear(3,3)) + BN3 partial sums
__global__ __launch_bounds__(256) void k_pr1(const float* __restrict__ p,
    const int* __restrict__ idx, const float* __restrict__ Wp1,
    const float* __restrict__ bp1, float* __restrict__ ws)
{
  float* pr1 = ws + OFF_PR1;
  float w00=Wp1[0],w01=Wp1[1],w02=Wp1[2];
  float w10=Wp1[3],w11=Wp1[4],w12=Wp1[5];
  float w20=Wp1[6],w21=Wp1[7],w22=Wp1[8];
  float b0=bp1[0],b1=bp1[1],b2=bp1[2];
  float s0=0,s1=0,s2=0,q0=0,q1=0,q2=0;
  int r0 = blockIdx.x*256 + threadIdx.x;
#pragma unroll
  for (int it = 0; it < 4; it++){
    int r = r0 + it*262144;
    int n = r >> 4;
    int iv = idx[r];
    float dx = p[iv*3+0] - p[n*3+0];
    float dy = p[iv*3+1] - p[n*3+1];
    float dz = p[iv*3+2] - p[n*3+2];
    float v0 = b0 + dx*w00 + dy*w01 + dz*w02;
    float v1 = b1 + dx*w10 + dy*w11 + dz*w12;
    float v2 = b2 + dx*w20 + dy*w21 + dz*w22;
    pr1[(size_t)r*3+0]=v0; pr1[(size_t)r*3+1]=v1; pr1[(size_t)r*3+2]=v2;
    s0+=v0; s1+=v1; s2+=v2;
    q0+=v0*v0; q1+=v1*v1; q2+=v2*v2;
  }
  s0=wave_sum(s0); s1=wave_sum(s1); s2=wave_sum(s2);
  q0=wave_sum(q0); q1=wave_sum(q1); q2=wave_sum(q2);
  __shared__ float lds[4][6];
  int lane = threadIdx.x & 63, wv = threadIdx.x >> 6;
  if (lane == 0){
    lds[wv][0]=s0; lds[wv][1]=s1; lds[wv][2]=s2;
    lds[wv][3]=q0; lds[wv][4]=q1; lds[wv][5]=q2;
  }
  __syncthreads();
  if (threadIdx.x < 6){
    float v = lds[0][threadIdx.x]+lds[1][threadIdx.x]+lds[2][threadIdx.x]+lds[3][threadIdx.x];
    atomicAdd(ws + (blockIdx.x & 7)*BANK_STRIDE + BOFF_S3S + threadIdx.x, v);
  }
}

// BN finalize from banked sums
__global__ void k_finalize(const float* __restrict__ ws, float* __restrict__ outf,
                           const float* __restrict__ g, const float* __restrict__ beta,
                           int nch, int sum_off, int sq_off)
{
  int t = threadIdx.x;
  if (t < nch){
    float s = 0.f, q = 0.f;
    for (int b = 0; b < BANKS; b++){
      s += ws[b*BANK_STRIDE + sum_off + t];
      q += ws[b*BANK_STRIDE + sq_off + t];
    }
    float invM = 1.0f / (float)NROWS;
    float mean = s * invM;
    float var  = q * invM - mean * mean;
    float rs   = rsqrtf(var + BN_EPS);
    float sc   = g[t] * rs;
    outf[t] = sc;
    outf[nch + t] = beta[t] - mean * sc;
  }
}

// BN64 stats. Wave-unit = (tileset, half-row). Tile = 16 rows of one point.
// Lane (r16,g): row r16 of tile, channels hoff + g*8 + j. Gather = one
// bf16x8 (16B) per lane -> 16 rows x 64B, fully coalesced. No LDS/shfl in loop.
__global__ __launch_bounds__(256) void k_stats64(const int* __restrict__ idx,
    const ushort_t* __restrict__ xqh, const ushort_t* __restrict__ xkh,
    const float* __restrict__ pr1, const float* __restrict__ f3,
    const float* __restrict__ Wp2, const float* __restrict__ bp2,
    float* __restrict__ ws)
{
  int lane = threadIdx.x & 63;
  int r16 = lane & 15, g = lane >> 4;
  int uid = __builtin_amdgcn_readfirstlane(blockIdx.x*4 + (threadIdx.x >> 6));
  int half = uid & 1;
  int t0 = (uid >> 1) * 16;          // 16 tiles per wave-unit
  int hoff = half * 32;

  float sc0=f3[0], sc1=f3[1], sc2=f3[2], sh0=f3[3], sh1=f3[4], sh2=f3[5];
  float wpa[8], wpb[8], wpc[8], bpv[8];
#pragma unroll
  for (int j = 0; j < 8; j++){
    int c = hoff + g*8 + j;
    wpa[j] = Wp2[c*3+0]; wpb[j] = Wp2[c*3+1]; wpc[j] = Wp2[c*3+2];
    bpv[j] = bp2[c];
  }
  float accs[8], accq[8];
#pragma unroll
  for (int j = 0; j < 8; j++){ accs[j]=0.f; accq[j]=0.f; }

  int tile = t0;
  int iv   = idx[tile*16 + r16];
  float a0 = pr1[(size_t)(tile*16+r16)*3+0];
  float a1 = pr1[(size_t)(tile*16+r16)*3+1];
  float a2 = pr1[(size_t)(tile*16+r16)*3+2];

#pragma unroll 1
  for (int t = 0; t < 16; t++){
    bf16x8 kk = *(const bf16x8*)(xkh + (size_t)iv*CH + hoff + g*8);
    bf16x8 qq = *(const bf16x8*)(xqh + (size_t)tile*CH + hoff + g*8);
    int ivn = 0; float c0=0.f, c1=0.f, c2=0.f;
    if (t < 15){
      int rn = (tile+1)*16 + r16;
      ivn = idx[rn];
      c0 = pr1[(size_t)rn*3+0]; c1 = pr1[(size_t)rn*3+1]; c2 = pr1[(size_t)rn*3+2];
    }
    float rb0 = fmaxf(fmaf(a0, sc0, sh0), 0.f);
    float rb1 = fmaxf(fmaf(a1, sc1, sh1), 0.f);
    float rb2 = fmaxf(fmaf(a2, sc2, sh2), 0.f);
#pragma unroll
    for (int j = 0; j < 8; j++){
      float pr2v = bpv[j] + rb0*wpa[j] + rb1*wpb[j] + rb2*wpc[j];
      float w = bf2f((ushort_t)kk[j]) - bf2f((ushort_t)qq[j]) + pr2v;
      accs[j] += w; accq[j] = fmaf(w, w, accq[j]);
    }
    tile++; iv = ivn; a0 = c0; a1 = c1; a2 = c2;
  }
  // reduce over r16 (bits 0..3)
#pragma unroll
  for (int j = 0; j < 8; j++){
#pragma unroll
    for (int m = 1; m <= 8; m <<= 1){
      accs[j] += __shfl_xor(accs[j], m);
      accq[j] += __shfl_xor(accq[j], m);
    }
  }
  if (r16 == 0){
    float* bank = ws + (blockIdx.x & 7)*BANK_STRIDE;
#pragma unroll
    for (int j = 0; j < 8; j++){
      atomicAdd(bank + BOFF_S64S + hoff + g*8 + j, accs[j]);
      atomicAdd(bank + BOFF_S64Q + hoff + g*8 + j, accq[j]);
    }
  }
}

// w2 = relu(bn64(w_pre)) @ Ww1^T + bw1 via MFMA. Wave per 16 tiles.
// A-frag: lane holds rb[row r16][ch g*8+j] (chunk0) / +32 (chunk1).
// B-frag: lane holds Ww1[o=(r16&7)][same ch]. D: col=r16 (o), row=g*4+reg.
__global__ __launch_bounds__(256) void k_w2(const int* __restrict__ idx,
    const ushort_t* __restrict__ xqh, const ushort_t* __restrict__ xkh,
    const float* __restrict__ pr1, const float* __restrict__ f3,
    const float* __restrict__ f64, const float* __restrict__ Wp2,
    const float* __restrict__ bp2, const float* __restrict__ Ww1,
    const float* __restrict__ bw1, float* __restrict__ w2o,
    float* __restrict__ ws)
{
  int lane = threadIdx.x & 63;
  int r16 = lane & 15, g = lane >> 4;
  int oc = r16 & 7;
  int t0 = __builtin_amdgcn_readfirstlane((blockIdx.x*4 + (threadIdx.x >> 6)) * 16);

  float sc30=f3[0], sc31=f3[1], sc32=f3[2], sh30=f3[3], sh31=f3[4], sh32=f3[5];
  float wpaL[8],wpbL[8],wpcL[8],bpL[8],bscL[8],bshL[8];
  float wpaH[8],wpbH[8],wpcH[8],bpH[8],bscH[8],bshH[8];
#pragma unroll
  for (int j = 0; j < 8; j++){
    int cL = g*8 + j, cH = cL + 32;
    wpaL[j]=Wp2[cL*3+0]; wpbL[j]=Wp2[cL*3+1]; wpcL[j]=Wp2[cL*3+2];
    bpL[j]=bp2[cL]; bscL[j]=f64[cL]; bshL[j]=f64[64+cL];
    wpaH[j]=Wp2[cH*3+0]; wpbH[j]=Wp2[cH*3+1]; wpcH[j]=Wp2[cH*3+2];
    bpH[j]=bp2[cH]; bscH[j]=f64[cH]; bshH[j]=f64[64+cH];
  }
  bf16x8 bf0, bf1;
#pragma unroll
  for (int j = 0; j < 8; j++){
    bf0[j] = (short)f2bf(Ww1[oc*CH + g*8 + j]);
    bf1[j] = (short)f2bf(Ww1[oc*CH + 32 + g*8 + j]);
  }
  float bwv = bw1[oc];

  float SB = 0.f, SQ = 0.f;

  int tile = t0;
  int iv   = idx[tile*16 + r16];
  float a0 = pr1[(size_t)(tile*16+r16)*3+0];
  float a1 = pr1[(size_t)(tile*16+r16)*3+1];
  float a2 = pr1[(size_t)(tile*16+r16)*3+2];

#pragma unroll 1
  for (int t = 0; t < 16; t++){
    bf16x8 k0 = *(const bf16x8*)(xkh + (size_t)iv*CH + g*8);
    bf16x8 k1 = *(const bf16x8*)(xkh + (size_t)iv*CH + 32 + g*8);
    bf16x8 q0 = *(const bf16x8*)(xqh + (size_t)tile*CH + g*8);
    bf16x8 q1 = *(const bf16x8*)(xqh + (size_t)tile*CH + 32 + g*8);
    int ivn = 0; float c0=0.f, c1=0.f, c2=0.f;
    if (t < 15){
      int rn = (tile+1)*16 + r16;
      ivn = idx[rn];
      c0 = pr1[(size_t)rn*3+0]; c1 = pr1[(size_t)rn*3+1]; c2 = pr1[(size_t)rn*3+2];
    }
    float rb0 = fmaxf(fmaf(a0, sc30, sh30), 0.f);
    float rb1 = fmaxf(fmaf(a1, sc31, sh31), 0.f);
    float rb2 = fmaxf(fmaf(a2, sc32, sh32), 0.f);
    bf16x8 af0, af1;
#pragma unroll
    for (int j = 0; j < 8; j++){
      float pr2L = bpL[j] + rb0*wpaL[j] + rb1*wpbL[j] + rb2*wpcL[j];
      float wL = bf2f((ushort_t)k0[j]) - bf2f((ushort_t)q0[j]) + pr2L;
      af0[j] = (short)f2bf(fmaxf(fmaf(wL, bscL[j], bshL[j]), 0.f));
      float pr2H = bpH[j] + rb0*wpaH[j] + rb1*wpbH[j] + rb2*wpcH[j];
      float wH = bf2f((ushort_t)k1[j]) - bf2f((ushort_t)q1[j]) + pr2H;
      af1[j] = (short)f2bf(fmaxf(fmaf(wH, bscH[j], bshH[j]), 0.f));
    }
    f32x4 d = {0.f, 0.f, 0.f, 0.f};
    d = __builtin_amdgcn_mfma_f32_16x16x32_bf16(af0, bf0, d, 0, 0, 0);
    d = __builtin_amdgcn_mfma_f32_16x16x32_bf16(af1, bf1, d, 0, 0, 0);
    int row0 = tile*16;
    float dv0 = d[0]+bwv, dv1 = d[1]+bwv, dv2 = d[2]+bwv, dv3 = d[3]+bwv;
    if (r16 < 8){
      w2o[(size_t)(row0 + g*4 + 0)*8 + r16] = dv0;
      w2o[(size_t)(row0 + g*4 + 1)*8 + r16] = dv1;
      w2o[(size_t)(row0 + g*4 + 2)*8 + r16] = dv2;
      w2o[(size_t)(row0 + g*4 + 3)*8 + r16] = dv3;
    }
    SB += dv0+dv1+dv2+dv3;
    SQ += dv0*dv0 + dv1*dv1 + dv2*dv2 + dv3*dv3;
    tile++; iv = ivn; a0 = c0; a1 = c1; a2 = c2;
  }
  SB += __shfl_xor(SB, 16); SB += __shfl_xor(SB, 32);
  SQ += __shfl_xor(SQ, 16); SQ += __shfl_xor(SQ, 32);
  if (lane < 8){
    float* bank = ws + (blockIdx.x & 7)*BANK_STRIDE;
    atomicAdd(bank + BOFF_S8S + lane, SB);
    atomicAdd(bank + BOFF_S8Q + lane, SQ);
  }
}

// final: w3 = relu(bn8(w2)) @ Ww2^T + bw2 ; softmax over 16 neighbors ;
// out = sum_j (xv+p_r2)*w. (round-4 form: uniform loads, no LDS in loop)
__global__ __launch_bounds__(256) void k_out(const int* __restrict__ idx,
    const ushort_t* __restrict__ xvh, const float* __restrict__ pr1,
    const float* __restrict__ w2, const float* __restrict__ f3,
    const float* __restrict__ f8, const float* __restrict__ Wp2,
    const float* __restrict__ bp2, const float* __restrict__ Ww2,
    const float* __restrict__ bw2, float* __restrict__ out)
{
  int lane = threadIdx.x & 63, wv = threadIdx.x >> 6;
  int n = __builtin_amdgcn_readfirstlane(blockIdx.x*4 + wv);
  int cp = lane & 7;
  int jg = lane >> 3;

  int iv[16]; float a0[16], a1[16], a2[16];
#pragma unroll
  for (int j = 0; j < 16; j++){
    int r = n*NSAMP + j;
    iv[j] = idx[r];
    a0[j] = pr1[(size_t)r*3+0];
    a1[j] = pr1[(size_t)r*3+1];
    a2[j] = pr1[(size_t)r*3+2];
  }
  ushort_t xvv[16];
#pragma unroll
  for (int j = 0; j < 16; j++) xvv[j] = xvh[(size_t)iv[j]*CH + lane];

  float wpa = Wp2[lane*3+0], wpb = Wp2[lane*3+1], wpc = Wp2[lane*3+2];
  float bp  = bp2[lane];
  float ww2_[8];
#pragma unroll
  for (int k = 0; k < 8; k++) ww2_[k] = Ww2[cp*8 + k];
  float bw = bw2[cp];
  float sc8[8], sh8[8];
#pragma unroll
  for (int k = 0; k < 8; k++){ sc8[k]=f8[k]; sh8[k]=f8[8+k]; }
  float sc30=f3[0], sc31=f3[1], sc32=f3[2], sh30=f3[3], sh31=f3[4], sh32=f3[5];

  const float4* ra  = (const float4*)(w2 + ((size_t)n*NSAMP + jg)*8);
  const float4* rbp = (const float4*)(w2 + ((size_t)n*NSAMP + jg + 8)*8);
  float4 A0 = ra[0],  A1 = ra[1];
  float4 B0 = rbp[0], B1 = rbp[1];
  float w3a = bw, w3b = bw;
#pragma unroll
  for (int k = 0; k < 8; k++){
    float va = (k < 4) ? ((k==0)?A0.x:(k==1)?A0.y:(k==2)?A0.z:A0.w)
                       : ((k==4)?A1.x:(k==5)?A1.y:(k==6)?A1.z:A1.w);
    float vb = (k < 4) ? ((k==0)?B0.x:(k==1)?B0.y:(k==2)?B0.z:B0.w)
                       : ((k==4)?B1.x:(k==5)?B1.y:(k==6)?B1.z:B1.w);
    float rba = fmaxf(va*sc8[k]+sh8[k], 0.0f);
    float rbb = fmaxf(vb*sc8[k]+sh8[k], 0.0f);
    w3a += rba * ww2_[k];
    w3b += rbb * ww2_[k];
  }

  float m = fmaxf(w3a, w3b);
#pragma unroll
  for (int mask = 8; mask <= 32; mask <<= 1) m = fmaxf(m, __shfl_xor(m, mask));
  float ea = expf(w3a - m), eb = expf(w3b - m);
  float ssum = ea + eb;
#pragma unroll
  for (int mask = 8; mask <= 32; mask <<= 1) ssum += __shfl_xor(ssum, mask);
  float inv = 1.0f / ssum;
  ea *= inv; eb *= inv;

  float oacc = 0.0f;
#pragma unroll
  for (int j = 0; j < NSAMP; j++){
    float wn = __shfl(j < 8 ? ea : eb, ((j & 7) << 3) | cp);
    float rb0 = fmaxf(fmaf(a0[j], sc30, sh30), 0.0f);
    float rb1 = fmaxf(fmaf(a1[j], sc31, sh31), 0.0f);
    float rb2 = fmaxf(fmaf(a2[j], sc32, sh32), 0.0f);
    float pr2v = bp + rb0*wpa + rb1*wpb + rb2*wpc;
    oacc += (bf2f(xvv[j]) + pr2v) * wn;
  }
  out[(size_t)n*CH + lane] = oacc;
}

extern "C" void kernel_launch(void* const* d_in, const int* in_sizes, int n_in,
                              void* d_out, int out_size, void* d_ws, size_t ws_size,
                              hipStream_t stream)
{
  const float* p    = (const float*)d_in[0];
  const float* x    = (const float*)d_in[1];
  const int*   idx  = (const int*)d_in[2];
  const float* Wq   = (const float*)d_in[3];
  const float* bq   = (const float*)d_in[4];
  const float* Wk   = (const float*)d_in[5];
  const float* bk   = (const float*)d_in[6];
  const float* Wv   = (const float*)d_in[7];
  const float* bv   = (const float*)d_in[8];
  const float* Wp1  = (const float*)d_in[9];
  const float* bp1  = (const float*)d_in[10];
  const float* gp   = (const float*)d_in[11];
  const float* betap= (const float*)d_in[12];
  const float* Wp2  = (const float*)d_in[13];
  const float* bp2  = (const float*)d_in[14];
  const float* gw1  = (const float*)d_in[15];
  const float* betaw1=(const float*)d_in[16];
  const float* Ww1  = (const float*)d_in[17];
  const float* bw1  = (const float*)d_in[18];
  const float* gw2  = (const float*)d_in[19];
  const float* betaw2=(const float*)d_in[20];
  const float* Ww2  = (const float*)d_in[21];
  const float* bw2  = (const float*)d_in[22];
  float* ws  = (float*)d_ws;
  float* out = (float*)d_out;

  ushort_t* xqh = (ushort_t*)(ws + OFF_XQH);
  ushort_t* xkh = (ushort_t*)(ws + OFF_XKH);
  ushort_t* xvh = (ushort_t*)(ws + OFF_XVH);

  k_zero<<<dim3(1), dim3(256), 0, stream>>>(ws);
  k_proj<<<dim3(NPTS/256, 3), dim3(256), 0, stream>>>(x, Wq,bq, Wk,bk, Wv,bv,
      xqh, xkh, xvh);
  k_pr1<<<dim3(1024), dim3(256), 0, stream>>>(p, idx, Wp1, bp1, ws);
  k_finalize<<<dim3(1), dim3(64), 0, stream>>>(ws, ws+OFF_F3, gp, betap,
      3, BOFF_S3S, BOFF_S3S+3);
  k_stats64<<<dim3(2048), dim3(256), 0, stream>>>(idx, xqh, xkh,
      ws+OFF_PR1, ws+OFF_F3, Wp2, bp2, ws);
  k_finalize<<<dim3(1), dim3(64), 0, stream>>>(ws, ws+OFF_F64, gw1, betaw1,
      64, BOFF_S64S, BOFF_S64Q);
  k_w2<<<dim3(1024), dim3(256), 0, stream>>>(idx, xqh, xkh, ws+OFF_PR1,
      ws+OFF_F3, ws+OFF_F64, Wp2, bp2, Ww1, bw1, ws+OFF_W2, ws);
  k_finalize<<<dim3(1), dim3(64), 0, stream>>>(ws, ws+OFF_F8, gw2, betaw2,
      8, BOFF_S8S, BOFF_S8Q);
  k_out<<<dim3(NPTS/4), dim3(256), 0, stream>>>(idx, xvh, ws+OFF_PR1, ws+OFF_W2,
      ws+OFF_F3, ws+OFF_F8, Wp2, bp2, Ww2, bw2, out);
}

// Round 8
// 386.513 us; speedup vs baseline: 2.1554x; 1.1174x over previous
//
#include <hip/hip_runtime.h>
#include <math.h>

typedef unsigned short ushort_t;
typedef unsigned int uint_t;
typedef __attribute__((ext_vector_type(8))) short bf16x8;
typedef __attribute__((ext_vector_type(4))) float f32x4;

#define NPTS 65536
#define NSAMP 16
#define CH 64
#define NROWS (NPTS*NSAMP)
#define NTILES (NROWS/16)
#define BN_EPS 1e-5f

// stat banks: 32 banks x 160 floats
#define BANKS 32
#define BANK_STRIDE 160
#define BOFF_S3S 0     // sum3[3] @0, sq3[3] @3
#define BOFF_S64S 16   // sum64[64] @16
#define BOFF_S64Q 80   // sq64[64] @80
#define BOFF_S8S 144   // sum8[8]
#define BOFF_S8Q 152   // sq8[8]
// finalized scale/shift
#define OFF_F3   5120  // scale3[3], shift3[3]
#define OFF_F64  5128  // scale64[64], shift64[64]
#define OFF_F8   5256  // scale8[8], shift8[8]
// big arrays (float offsets)
#define OFF_XQH  5376
#define OFF_XKH  (OFF_XQH + NPTS*CH/2)
#define OFF_XVH  (OFF_XKH + NPTS*CH/2)
#define OFF_PR1  (OFF_XVH + NPTS*CH/2)
#define OFF_W2   (OFF_PR1 + (size_t)NROWS*3)
// total ~17.8M floats ~71MB

__device__ __forceinline__ float wave_sum(float v){
#pragma unroll
  for (int m = 32; m > 0; m >>= 1) v += __shfl_xor(v, m);
  return v;
}
__device__ __forceinline__ ushort_t f2bf(float f){
  uint_t u = __float_as_uint(f);
  u += 0x7fffu + ((u >> 16) & 1u);
  return (ushort_t)(u >> 16);
}
__device__ __forceinline__ float bf2f(ushort_t h){
  return __uint_as_float(((uint_t)h) << 16);
}

__global__ void k_zero(float* __restrict__ ws){
  for (int i = threadIdx.x; i < 5376; i += 256) ws[i] = 0.0f;
}

// q/k/v projections -> bf16 outputs
__global__ __launch_bounds__(256) void k_proj(const float* __restrict__ x,
    const float* __restrict__ W0, const float* __restrict__ b0,
    const float* __restrict__ W1, const float* __restrict__ b1,
    const float* __restrict__ W2, const float* __restrict__ b2,
    ushort_t* __restrict__ xqh, ushort_t* __restrict__ xkh, ushort_t* __restrict__ xvh)
{
  int n = blockIdx.x * blockDim.x + threadIdx.x;
  const float* W; const float* b; ushort_t* outp;
  if (blockIdx.y == 0)      { W = W0; b = b0; outp = xqh; }
  else if (blockIdx.y == 1) { W = W1; b = b1; outp = xkh; }
  else                      { W = W2; b = b2; outp = xvh; }

  float4 xr[16];
  const float4* xp = (const float4*)(x + (size_t)n * CH);
#pragma unroll
  for (int i = 0; i < 16; i++) xr[i] = xp[i];

  ushort_t* oph = outp + (size_t)n * CH;
#pragma unroll 1
  for (int o4 = 0; o4 < 16; o4++){
    float a[4];
#pragma unroll
    for (int oo = 0; oo < 4; oo++){
      int o = o4 * 4 + oo;
      float acc = b[o];
      const float4* wp = (const float4*)(W + o * CH);
#pragma unroll
      for (int i = 0; i < 16; i++){
        float4 w4 = wp[i];
        acc += xr[i].x * w4.x + xr[i].y * w4.y + xr[i].z * w4.z + xr[i].w * w4.w;
      }
      a[oo] = acc;
    }
    uint2 st;
    st.x = (uint_t)f2bf(a[0]) | ((uint_t)f2bf(a[1]) << 16);
    st.y = (uint_t)f2bf(a[2]) | ((uint_t)f2bf(a[3]) << 16);
    ((uint2*)oph)[o4] = st;
  }
}

// p_r stage 1 (Linear(3,3)) + BN3 partial sums
__global__ __launch_bounds__(256) void k_pr1(const float* __restrict__ p,
    const int* __restrict__ idx, const float* __restrict__ Wp1,
    const float* __restrict__ bp1, float* __restrict__ ws)
{
  float* pr1 = ws + OFF_PR1;
  float w00=Wp1[0],w01=Wp1[1],w02=Wp1[2];
  float w10=Wp1[3],w11=Wp1[4],w12=Wp1[5];
  float w20=Wp1[6],w21=Wp1[7],w22=Wp1[8];
  float b0=bp1[0],b1=bp1[1],b2=bp1[2];
  float s0=0,s1=0,s2=0,q0=0,q1=0,q2=0;
  int r0 = blockIdx.x*256 + threadIdx.x;
#pragma unroll
  for (int it = 0; it < 4; it++){
    int r = r0 + it*262144;
    int n = r >> 4;
    int iv = idx[r];
    float dx = p[iv*3+0] - p[n*3+0];
    float dy = p[iv*3+1] - p[n*3+1];
    float dz = p[iv*3+2] - p[n*3+2];
    float v0 = b0 + dx*w00 + dy*w01 + dz*w02;
    float v1 = b1 + dx*w10 + dy*w11 + dz*w12;
    float v2 = b2 + dx*w20 + dy*w21 + dz*w22;
    pr1[(size_t)r*3+0]=v0; pr1[(size_t)r*3+1]=v1; pr1[(size_t)r*3+2]=v2;
    s0+=v0; s1+=v1; s2+=v2;
    q0+=v0*v0; q1+=v1*v1; q2+=v2*v2;
  }
  s0=wave_sum(s0); s1=wave_sum(s1); s2=wave_sum(s2);
  q0=wave_sum(q0); q1=wave_sum(q1); q2=wave_sum(q2);
  __shared__ float lds[4][6];
  int lane = threadIdx.x & 63, wv = threadIdx.x >> 6;
  if (lane == 0){
    lds[wv][0]=s0; lds[wv][1]=s1; lds[wv][2]=s2;
    lds[wv][3]=q0; lds[wv][4]=q1; lds[wv][5]=q2;
  }
  __syncthreads();
  if (threadIdx.x < 6){
    float v = lds[0][threadIdx.x]+lds[1][threadIdx.x]+lds[2][threadIdx.x]+lds[3][threadIdx.x];
    atomicAdd(ws + (blockIdx.x & (BANKS-1))*BANK_STRIDE + BOFF_S3S + threadIdx.x, v);
  }
}

// BN finalize from banked sums
__global__ void k_finalize(const float* __restrict__ ws, float* __restrict__ outf,
                           const float* __restrict__ g, const float* __restrict__ beta,
                           int nch, int sum_off, int sq_off)
{
  int t = threadIdx.x;
  if (t < nch){
    float s = 0.f, q = 0.f;
    for (int b = 0; b < BANKS; b++){
      s += ws[b*BANK_STRIDE + sum_off + t];
      q += ws[b*BANK_STRIDE + sq_off + t];
    }
    float invM = 1.0f / (float)NROWS;
    float mean = s * invM;
    float var  = q * invM - mean * mean;
    float rs   = rsqrtf(var + BN_EPS);
    float sc   = g[t] * rs;
    outf[t] = sc;
    outf[nch + t] = beta[t] - mean * sc;
  }
}

// BN64 stats over w_pre = xk[idx] - xq + p_r2.
// Wave-unit = 4 tiles x one channel-half, FULLY FLATTENED: all idx/pr1/xq
// loads issue first, then all 4 gathers -> ~24 loads in flight, 2 latency
// exposures instead of 16. Grid 8192 blocks (32768 wave-units).
__global__ __launch_bounds__(256) void k_stats64(const int* __restrict__ idx,
    const ushort_t* __restrict__ xqh, const ushort_t* __restrict__ xkh,
    const float* __restrict__ pr1, const float* __restrict__ f3,
    const float* __restrict__ Wp2, const float* __restrict__ bp2,
    float* __restrict__ ws)
{
  int lane = threadIdx.x & 63;
  int r16 = lane & 15, g = lane >> 4;
  int wv = threadIdx.x >> 6;
  int uid = __builtin_amdgcn_readfirstlane(blockIdx.x*4 + wv);
  int half = uid & 1;
  int t0 = (uid >> 1) * 4;           // 4 tiles per wave-unit
  int hoff = half * 32;

  // phase A: per-lane idx + pr1 rows (all independent, issue together)
  int r0 = (t0+0)*16 + r16, r1 = (t0+1)*16 + r16;
  int r2 = (t0+2)*16 + r16, r3 = (t0+3)*16 + r16;
  int iv0 = idx[r0], iv1 = idx[r1], iv2 = idx[r2], iv3 = idx[r3];
  float a00=pr1[(size_t)r0*3+0], a01=pr1[(size_t)r0*3+1], a02=pr1[(size_t)r0*3+2];
  float a10=pr1[(size_t)r1*3+0], a11=pr1[(size_t)r1*3+1], a12=pr1[(size_t)r1*3+2];
  float a20=pr1[(size_t)r2*3+0], a21=pr1[(size_t)r2*3+1], a22=pr1[(size_t)r2*3+2];
  float a30=pr1[(size_t)r3*3+0], a31=pr1[(size_t)r3*3+1], a32=pr1[(size_t)r3*3+2];

  // xq broadcasts (per tile, shared by the 16 r16-lanes of each g group)
  bf16x8 q0 = *(const bf16x8*)(xqh + (size_t)(t0+0)*CH + hoff + g*8);
  bf16x8 q1 = *(const bf16x8*)(xqh + (size_t)(t0+1)*CH + hoff + g*8);
  bf16x8 q2 = *(const bf16x8*)(xqh + (size_t)(t0+2)*CH + hoff + g*8);
  bf16x8 q3 = *(const bf16x8*)(xqh + (size_t)(t0+3)*CH + hoff + g*8);

  // phase B: all 4 gathers (wait only on their own iv)
  bf16x8 k0 = *(const bf16x8*)(xkh + (size_t)iv0*CH + hoff + g*8);
  bf16x8 k1 = *(const bf16x8*)(xkh + (size_t)iv1*CH + hoff + g*8);
  bf16x8 k2 = *(const bf16x8*)(xkh + (size_t)iv2*CH + hoff + g*8);
  bf16x8 k3 = *(const bf16x8*)(xkh + (size_t)iv3*CH + hoff + g*8);

  // per-lane channel constants
  float sc0=f3[0], sc1=f3[1], sc2=f3[2], sh0=f3[3], sh1=f3[4], sh2=f3[5];
  float wpa[8], wpb[8], wpc[8], bpv[8];
#pragma unroll
  for (int j = 0; j < 8; j++){
    int c = hoff + g*8 + j;
    wpa[j] = Wp2[c*3+0]; wpb[j] = Wp2[c*3+1]; wpc[j] = Wp2[c*3+2];
    bpv[j] = bp2[c];
  }

  float accs[8], accq[8];
#pragma unroll
  for (int j = 0; j < 8; j++){ accs[j]=0.f; accq[j]=0.f; }

  float rb00 = fmaxf(fmaf(a00, sc0, sh0), 0.f), rb01 = fmaxf(fmaf(a01, sc1, sh1), 0.f), rb02 = fmaxf(fmaf(a02, sc2, sh2), 0.f);
  float rb10 = fmaxf(fmaf(a10, sc0, sh0), 0.f), rb11 = fmaxf(fmaf(a11, sc1, sh1), 0.f), rb12 = fmaxf(fmaf(a12, sc2, sh2), 0.f);
  float rb20 = fmaxf(fmaf(a20, sc0, sh0), 0.f), rb21 = fmaxf(fmaf(a21, sc1, sh1), 0.f), rb22 = fmaxf(fmaf(a22, sc2, sh2), 0.f);
  float rb30 = fmaxf(fmaf(a30, sc0, sh0), 0.f), rb31 = fmaxf(fmaf(a31, sc1, sh1), 0.f), rb32 = fmaxf(fmaf(a32, sc2, sh2), 0.f);

#pragma unroll
  for (int j = 0; j < 8; j++){
    float w;
    w = bf2f((ushort_t)k0[j]) - bf2f((ushort_t)q0[j])
      + bpv[j] + rb00*wpa[j] + rb01*wpb[j] + rb02*wpc[j];
    accs[j] += w; accq[j] = fmaf(w, w, accq[j]);
    w = bf2f((ushort_t)k1[j]) - bf2f((ushort_t)q1[j])
      + bpv[j] + rb10*wpa[j] + rb11*wpb[j] + rb12*wpc[j];
    accs[j] += w; accq[j] = fmaf(w, w, accq[j]);
    w = bf2f((ushort_t)k2[j]) - bf2f((ushort_t)q2[j])
      + bpv[j] + rb20*wpa[j] + rb21*wpb[j] + rb22*wpc[j];
    accs[j] += w; accq[j] = fmaf(w, w, accq[j]);
    w = bf2f((ushort_t)k3[j]) - bf2f((ushort_t)q3[j])
      + bpv[j] + rb30*wpa[j] + rb31*wpb[j] + rb32*wpc[j];
    accs[j] += w; accq[j] = fmaf(w, w, accq[j]);
  }

  // reduce over r16 (lane bits 0..3)
#pragma unroll
  for (int j = 0; j < 8; j++){
#pragma unroll
    for (int m = 1; m <= 8; m <<= 1){
      accs[j] += __shfl_xor(accs[j], m);
      accq[j] += __shfl_xor(accq[j], m);
    }
  }
  if (r16 == 0){
    float* bank = ws + (uid & (BANKS-1))*BANK_STRIDE;
#pragma unroll
    for (int j = 0; j < 8; j++){
      atomicAdd(bank + BOFF_S64S + hoff + g*8 + j, accs[j]);
      atomicAdd(bank + BOFF_S64Q + hoff + g*8 + j, accq[j]);
    }
  }
}

// w2 = relu(bn64(w_pre)) @ Ww1^T + bw1 via MFMA. Wave per 16 tiles.
// A-frag: lane holds rb[row r16][ch g*8+j] (chunk0) / +32 (chunk1).
// B-frag: lane holds Ww1[o=(r16&7)][same ch]. D: col=r16 (o), row=g*4+reg.
__global__ __launch_bounds__(256) void k_w2(const int* __restrict__ idx,
    const ushort_t* __restrict__ xqh, const ushort_t* __restrict__ xkh,
    const float* __restrict__ pr1, const float* __restrict__ f3,
    const float* __restrict__ f64, const float* __restrict__ Wp2,
    const float* __restrict__ bp2, const float* __restrict__ Ww1,
    const float* __restrict__ bw1, float* __restrict__ w2o,
    float* __restrict__ ws)
{
  int lane = threadIdx.x & 63;
  int r16 = lane & 15, g = lane >> 4;
  int oc = r16 & 7;
  int t0 = __builtin_amdgcn_readfirstlane((blockIdx.x*4 + (threadIdx.x >> 6)) * 16);

  float sc30=f3[0], sc31=f3[1], sc32=f3[2], sh30=f3[3], sh31=f3[4], sh32=f3[5];
  float wpaL[8],wpbL[8],wpcL[8],bpL[8],bscL[8],bshL[8];
  float wpaH[8],wpbH[8],wpcH[8],bpH[8],bscH[8],bshH[8];
#pragma unroll
  for (int j = 0; j < 8; j++){
    int cL = g*8 + j, cH = cL + 32;
    wpaL[j]=Wp2[cL*3+0]; wpbL[j]=Wp2[cL*3+1]; wpcL[j]=Wp2[cL*3+2];
    bpL[j]=bp2[cL]; bscL[j]=f64[cL]; bshL[j]=f64[64+cL];
    wpaH[j]=Wp2[cH*3+0]; wpbH[j]=Wp2[cH*3+1]; wpcH[j]=Wp2[cH*3+2];
    bpH[j]=bp2[cH]; bscH[j]=f64[cH]; bshH[j]=f64[64+cH];
  }
  bf16x8 bf0, bf1;
#pragma unroll
  for (int j = 0; j < 8; j++){
    bf0[j] = (short)f2bf(Ww1[oc*CH + g*8 + j]);
    bf1[j] = (short)f2bf(Ww1[oc*CH + 32 + g*8 + j]);
  }
  float bwv = bw1[oc];

  float SB = 0.f, SQ = 0.f;

  int tile = t0;
  int iv   = idx[tile*16 + r16];
  float a0 = pr1[(size_t)(tile*16+r16)*3+0];
  float a1 = pr1[(size_t)(tile*16+r16)*3+1];
  float a2 = pr1[(size_t)(tile*16+r16)*3+2];

#pragma unroll 1
  for (int t = 0; t < 16; t++){
    bf16x8 k0 = *(const bf16x8*)(xkh + (size_t)iv*CH + g*8);
    bf16x8 k1 = *(const bf16x8*)(xkh + (size_t)iv*CH + 32 + g*8);
    bf16x8 q0 = *(const bf16x8*)(xqh + (size_t)tile*CH + g*8);
    bf16x8 q1 = *(const bf16x8*)(xqh + (size_t)tile*CH + 32 + g*8);
    int ivn = 0; float c0=0.f, c1=0.f, c2=0.f;
    if (t < 15){
      int rn = (tile+1)*16 + r16;
      ivn = idx[rn];
      c0 = pr1[(size_t)rn*3+0]; c1 = pr1[(size_t)rn*3+1]; c2 = pr1[(size_t)rn*3+2];
    }
    float rb0 = fmaxf(fmaf(a0, sc30, sh30), 0.f);
    float rb1 = fmaxf(fmaf(a1, sc31, sh31), 0.f);
    float rb2 = fmaxf(fmaf(a2, sc32, sh32), 0.f);
    bf16x8 af0, af1;
#pragma unroll
    for (int j = 0; j < 8; j++){
      float pr2L = bpL[j] + rb0*wpaL[j] + rb1*wpbL[j] + rb2*wpcL[j];
      float wL = bf2f((ushort_t)k0[j]) - bf2f((ushort_t)q0[j]) + pr2L;
      af0[j] = (short)f2bf(fmaxf(fmaf(wL, bscL[j], bshL[j]), 0.f));
      float pr2H = bpH[j] + rb0*wpaH[j] + rb1*wpbH[j] + rb2*wpcH[j];
      float wH = bf2f((ushort_t)k1[j]) - bf2f((ushort_t)q1[j]) + pr2H;
      af1[j] = (short)f2bf(fmaxf(fmaf(wH, bscH[j], bshH[j]), 0.f));
    }
    f32x4 d = {0.f, 0.f, 0.f, 0.f};
    d = __builtin_amdgcn_mfma_f32_16x16x32_bf16(af0, bf0, d, 0, 0, 0);
    d = __builtin_amdgcn_mfma_f32_16x16x32_bf16(af1, bf1, d, 0, 0, 0);
    int row0 = tile*16;
    float dv0 = d[0]+bwv, dv1 = d[1]+bwv, dv2 = d[2]+bwv, dv3 = d[3]+bwv;
    if (r16 < 8){
      w2o[(size_t)(row0 + g*4 + 0)*8 + r16] = dv0;
      w2o[(size_t)(row0 + g*4 + 1)*8 + r16] = dv1;
      w2o[(size_t)(row0 + g*4 + 2)*8 + r16] = dv2;
      w2o[(size_t)(row0 + g*4 + 3)*8 + r16] = dv3;
    }
    SB += dv0+dv1+dv2+dv3;
    SQ += dv0*dv0 + dv1*dv1 + dv2*dv2 + dv3*dv3;
    tile++; iv = ivn; a0 = c0; a1 = c1; a2 = c2;
  }
  SB += __shfl_xor(SB, 16); SB += __shfl_xor(SB, 32);
  SQ += __shfl_xor(SQ, 16); SQ += __shfl_xor(SQ, 32);
  if (lane < 8){
    float* bank = ws + (blockIdx.x & (BANKS-1))*BANK_STRIDE;
    atomicAdd(bank + BOFF_S8S + lane, SB);
    atomicAdd(bank + BOFF_S8Q + lane, SQ);
  }
}

// final: w3 = relu(bn8(w2)) @ Ww2^T + bw2 ; softmax over 16 neighbors ;
// out = sum_j (xv+p_r2)*w. (round-4 form: uniform loads, no LDS in loop)
__global__ __launch_bounds__(256) void k_out(const int* __restrict__ idx,
    const ushort_t* __restrict__ xvh, const float* __restrict__ pr1,
    const float* __restrict__ w2, const float* __restrict__ f3,
    const float* __restrict__ f8, const float* __restrict__ Wp2,
    const float* __restrict__ bp2, const float* __restrict__ Ww2,
    const float* __restrict__ bw2, float* __restrict__ out)
{
  int lane = threadIdx.x & 63, wv = threadIdx.x >> 6;
  int n = __builtin_amdgcn_readfirstlane(blockIdx.x*4 + wv);
  int cp = lane & 7;
  int jg = lane >> 3;

  int iv[16]; float a0[16], a1[16], a2[16];
#pragma unroll
  for (int j = 0; j < 16; j++){
    int r = n*NSAMP + j;
    iv[j] = idx[r];
    a0[j] = pr1[(size_t)r*3+0];
    a1[j] = pr1[(size_t)r*3+1];
    a2[j] = pr1[(size_t)r*3+2];
  }
  ushort_t xvv[16];
#pragma unroll
  for (int j = 0; j < 16; j++) xvv[j] = xvh[(size_t)iv[j]*CH + lane];

  float wpa = Wp2[lane*3+0], wpb = Wp2[lane*3+1], wpc = Wp2[lane*3+2];
  float bp  = bp2[lane];
  float ww2_[8];
#pragma unroll
  for (int k = 0; k < 8; k++) ww2_[k] = Ww2[cp*8 + k];
  float bw = bw2[cp];
  float sc8[8], sh8[8];
#pragma unroll
  for (int k = 0; k < 8; k++){ sc8[k]=f8[k]; sh8[k]=f8[8+k]; }
  float sc30=f3[0], sc31=f3[1], sc32=f3[2], sh30=f3[3], sh31=f3[4], sh32=f3[5];

  const float4* ra  = (const float4*)(w2 + ((size_t)n*NSAMP + jg)*8);
  const float4* rbp = (const float4*)(w2 + ((size_t)n*NSAMP + jg + 8)*8);
  float4 A0 = ra[0],  A1 = ra[1];
  float4 B0 = rbp[0], B1 = rbp[1];
  float w3a = bw, w3b = bw;
#pragma unroll
  for (int k = 0; k < 8; k++){
    float va = (k < 4) ? ((k==0)?A0.x:(k==1)?A0.y:(k==2)?A0.z:A0.w)
                       : ((k==4)?A1.x:(k==5)?A1.y:(k==6)?A1.z:A1.w);
    float vb = (k < 4) ? ((k==0)?B0.x:(k==1)?B0.y:(k==2)?B0.z:B0.w)
                       : ((k==4)?B1.x:(k==5)?B1.y:(k==6)?B1.z:B1.w);
    float rba = fmaxf(va*sc8[k]+sh8[k], 0.0f);
    float rbb = fmaxf(vb*sc8[k]+sh8[k], 0.0f);
    w3a += rba * ww2_[k];
    w3b += rbb * ww2_[k];
  }

  float m = fmaxf(w3a, w3b);
#pragma unroll
  for (int mask = 8; mask <= 32; mask <<= 1) m = fmaxf(m, __shfl_xor(m, mask));
  float ea = expf(w3a - m), eb = expf(w3b - m);
  float ssum = ea + eb;
#pragma unroll
  for (int mask = 8; mask <= 32; mask <<= 1) ssum += __shfl_xor(ssum, mask);
  float inv = 1.0f / ssum;
  ea *= inv; eb *= inv;

  float oacc = 0.0f;
#pragma unroll
  for (int j = 0; j < NSAMP; j++){
    float wn = __shfl(j < 8 ? ea : eb, ((j & 7) << 3) | cp);
    float rb0 = fmaxf(fmaf(a0[j], sc30, sh30), 0.0f);
    float rb1 = fmaxf(fmaf(a1[j], sc31, sh31), 0.0f);
    float rb2 = fmaxf(fmaf(a2[j], sc32, sh32), 0.0f);
    float pr2v = bp + rb0*wpa + rb1*wpb + rb2*wpc;
    oacc += (bf2f(xvv[j]) + pr2v) * wn;
  }
  out[(size_t)n*CH + lane] = oacc;
}

extern "C" void kernel_launch(void* const* d_in, const int* in_sizes, int n_in,
                              void* d_out, int out_size, void* d_ws, size_t ws_size,
                              hipStream_t stream)
{
  const float* p    = (const float*)d_in[0];
  const float* x    = (const float*)d_in[1];
  const int*   idx  = (const int*)d_in[2];
  const float* Wq   = (const float*)d_in[3];
  const float* bq   = (const float*)d_in[4];
  const float* Wk   = (const float*)d_in[5];
  const float* bk   = (const float*)d_in[6];
  const float* Wv   = (const float*)d_in[7];
  const float* bv   = (const float*)d_in[8];
  const float* Wp1  = (const float*)d_in[9];
  const float* bp1  = (const float*)d_in[10];
  const float* gp   = (const float*)d_in[11];
  const float* betap= (const float*)d_in[12];
  const float* Wp2  = (const float*)d_in[13];
  const float* bp2  = (const float*)d_in[14];
  const float* gw1  = (const float*)d_in[15];
  const float* betaw1=(const float*)d_in[16];
  const float* Ww1  = (const float*)d_in[17];
  const float* bw1  = (const float*)d_in[18];
  const float* gw2  = (const float*)d_in[19];
  const float* betaw2=(const float*)d_in[20];
  const float* Ww2  = (const float*)d_in[21];
  const float* bw2  = (const float*)d_in[22];
  float* ws  = (float*)d_ws;
  float* out = (float*)d_out;

  ushort_t* xqh = (ushort_t*)(ws + OFF_XQH);
  ushort_t* xkh = (ushort_t*)(ws + OFF_XKH);
  ushort_t* xvh = (ushort_t*)(ws + OFF_XVH);

  k_zero<<<dim3(1), dim3(256), 0, stream>>>(ws);
  k_proj<<<dim3(NPTS/256, 3), dim3(256), 0, stream>>>(x, Wq,bq, Wk,bk, Wv,bv,
      xqh, xkh, xvh);
  k_pr1<<<dim3(1024), dim3(256), 0, stream>>>(p, idx, Wp1, bp1, ws);
  k_finalize<<<dim3(1), dim3(64), 0, stream>>>(ws, ws+OFF_F3, gp, betap,
      3, BOFF_S3S, BOFF_S3S+3);
  k_stats64<<<dim3(8192), dim3(256), 0, stream>>>(idx, xqh, xkh,
      ws+OFF_PR1, ws+OFF_F3, Wp2, bp2, ws);
  k_finalize<<<dim3(1), dim3(64), 0, stream>>>(ws, ws+OFF_F64, gw1, betaw1,
      64, BOFF_S64S, BOFF_S64Q);
  k_w2<<<dim3(1024), dim3(256), 0, stream>>>(idx, xqh, xkh, ws+OFF_PR1,
      ws+OFF_F3, ws+OFF_F64, Wp2, bp2, Ww1, bw1, ws+OFF_W2, ws);
  k_finalize<<<dim3(1), dim3(64), 0, stream>>>(ws, ws+OFF_F8, gw2, betaw2,
      8, BOFF_S8S, BOFF_S8Q);
  k_out<<<dim3(NPTS/4), dim3(256), 0, stream>>>(idx, xvh, ws+OFF_PR1, ws+OFF_W2,
      ws+OFF_F3, ws+OFF_F8, Wp2, bp2, Ww2, bw2, out);
}

// Round 9
// 317.166 us; speedup vs baseline: 2.6267x; 1.2186x over previous
//
#include <hip/hip_runtime.h>
#include <math.h>

typedef unsigned short ushort_t;
typedef unsigned int uint_t;
typedef __attribute__((ext_vector_type(8))) short bf16x8;
typedef __attribute__((ext_vector_type(4))) float f32x4;

#define NPTS 65536
#define NSAMP 16
#define CH 64
#define NROWS (NPTS*NSAMP)
#define NTILES (NROWS/16)
#define BN_EPS 1e-5f

// stat banks: 32 banks x 160 floats
#define BANKS 32
#define BANK_STRIDE 160
#define BOFF_S3S 0     // sum3[3] @0, sq3[3] @3
#define BOFF_S64S 16   // sum64[64] @16
#define BOFF_S64Q 80   // sq64[64] @80
#define BOFF_S8S 144   // sum8[8]
#define BOFF_S8Q 152   // sq8[8]
// finalized scale/shift
#define OFF_F3   5120  // scale3[3], shift3[3]
#define OFF_F64  5128  // scale64[64], shift64[64]
#define OFF_F8   5256  // scale8[8], shift8[8]
// big arrays (float offsets)
#define OFF_XQH  5376
#define OFF_XKH  (OFF_XQH + NPTS*CH/2)
#define OFF_XVH  (OFF_XKH + NPTS*CH/2)
#define OFF_PR1  (OFF_XVH + NPTS*CH/2)
#define OFF_W2   (OFF_PR1 + (size_t)NROWS*3)
// total ~17.8M floats ~71MB

__device__ __forceinline__ float wave_sum(float v){
#pragma unroll
  for (int m = 32; m > 0; m >>= 1) v += __shfl_xor(v, m);
  return v;
}
__device__ __forceinline__ ushort_t f2bf(float f){
  uint_t u = __float_as_uint(f);
  u += 0x7fffu + ((u >> 16) & 1u);
  return (ushort_t)(u >> 16);
}
__device__ __forceinline__ float bf2f(ushort_t h){
  return __uint_as_float(((uint_t)h) << 16);
}

__global__ void k_zero(float* __restrict__ ws){
  for (int i = threadIdx.x; i < 5376; i += 256) ws[i] = 0.0f;
}

// q/k/v projections -> bf16 outputs
__global__ __launch_bounds__(256) void k_proj(const float* __restrict__ x,
    const float* __restrict__ W0, const float* __restrict__ b0,
    const float* __restrict__ W1, const float* __restrict__ b1,
    const float* __restrict__ W2, const float* __restrict__ b2,
    ushort_t* __restrict__ xqh, ushort_t* __restrict__ xkh, ushort_t* __restrict__ xvh)
{
  int n = blockIdx.x * blockDim.x + threadIdx.x;
  const float* W; const float* b; ushort_t* outp;
  if (blockIdx.y == 0)      { W = W0; b = b0; outp = xqh; }
  else if (blockIdx.y == 1) { W = W1; b = b1; outp = xkh; }
  else                      { W = W2; b = b2; outp = xvh; }

  float4 xr[16];
  const float4* xp = (const float4*)(x + (size_t)n * CH);
#pragma unroll
  for (int i = 0; i < 16; i++) xr[i] = xp[i];

  ushort_t* oph = outp + (size_t)n * CH;
#pragma unroll 1
  for (int o4 = 0; o4 < 16; o4++){
    float a[4];
#pragma unroll
    for (int oo = 0; oo < 4; oo++){
      int o = o4 * 4 + oo;
      float acc = b[o];
      const float4* wp = (const float4*)(W + o * CH);
#pragma unroll
      for (int i = 0; i < 16; i++){
        float4 w4 = wp[i];
        acc += xr[i].x * w4.x + xr[i].y * w4.y + xr[i].z * w4.z + xr[i].w * w4.w;
      }
      a[oo] = acc;
    }
    uint2 st;
    st.x = (uint_t)f2bf(a[0]) | ((uint_t)f2bf(a[1]) << 16);
    st.y = (uint_t)f2bf(a[2]) | ((uint_t)f2bf(a[3]) << 16);
    ((uint2*)oph)[o4] = st;
  }
}

// p_r stage 1 (Linear(3,3)) + BN3 partial sums
__global__ __launch_bounds__(256) void k_pr1(const float* __restrict__ p,
    const int* __restrict__ idx, const float* __restrict__ Wp1,
    const float* __restrict__ bp1, float* __restrict__ ws)
{
  float* pr1 = ws + OFF_PR1;
  float w00=Wp1[0],w01=Wp1[1],w02=Wp1[2];
  float w10=Wp1[3],w11=Wp1[4],w12=Wp1[5];
  float w20=Wp1[6],w21=Wp1[7],w22=Wp1[8];
  float b0=bp1[0],b1=bp1[1],b2=bp1[2];
  float s0=0,s1=0,s2=0,q0=0,q1=0,q2=0;
  int r0 = blockIdx.x*256 + threadIdx.x;
#pragma unroll
  for (int it = 0; it < 4; it++){
    int r = r0 + it*262144;
    int n = r >> 4;
    int iv = idx[r];
    float dx = p[iv*3+0] - p[n*3+0];
    float dy = p[iv*3+1] - p[n*3+1];
    float dz = p[iv*3+2] - p[n*3+2];
    float v0 = b0 + dx*w00 + dy*w01 + dz*w02;
    float v1 = b1 + dx*w10 + dy*w11 + dz*w12;
    float v2 = b2 + dx*w20 + dy*w21 + dz*w22;
    pr1[(size_t)r*3+0]=v0; pr1[(size_t)r*3+1]=v1; pr1[(size_t)r*3+2]=v2;
    s0+=v0; s1+=v1; s2+=v2;
    q0+=v0*v0; q1+=v1*v1; q2+=v2*v2;
  }
  s0=wave_sum(s0); s1=wave_sum(s1); s2=wave_sum(s2);
  q0=wave_sum(q0); q1=wave_sum(q1); q2=wave_sum(q2);
  __shared__ float lds[4][6];
  int lane = threadIdx.x & 63, wv = threadIdx.x >> 6;
  if (lane == 0){
    lds[wv][0]=s0; lds[wv][1]=s1; lds[wv][2]=s2;
    lds[wv][3]=q0; lds[wv][4]=q1; lds[wv][5]=q2;
  }
  __syncthreads();
  if (threadIdx.x < 6){
    float v = lds[0][threadIdx.x]+lds[1][threadIdx.x]+lds[2][threadIdx.x]+lds[3][threadIdx.x];
    atomicAdd(ws + (blockIdx.x & (BANKS-1))*BANK_STRIDE + BOFF_S3S + threadIdx.x, v);
  }
}

// BN finalize from banked sums
__global__ void k_finalize(const float* __restrict__ ws, float* __restrict__ outf,
                           const float* __restrict__ g, const float* __restrict__ beta,
                           int nch, int sum_off, int sq_off)
{
  int t = threadIdx.x;
  if (t < nch){
    float s = 0.f, q = 0.f;
    for (int b = 0; b < BANKS; b++){
      s += ws[b*BANK_STRIDE + sum_off + t];
      q += ws[b*BANK_STRIDE + sq_off + t];
    }
    float invM = 1.0f / (float)NROWS;
    float mean = s * invM;
    float var  = q * invM - mean * mean;
    float rs   = rsqrtf(var + BN_EPS);
    float sc   = g[t] * rs;
    outf[t] = sc;
    outf[nch + t] = beta[t] - mean * sc;
  }
}

// BN64 stats over w_pre = xk[idx] - xq + p_r2.
// Wave-unit = 8 tiles x one channel-half, FULLY FLATTENED: 8 idx + 24 pr1
// loads issue, then all 8 xk-gathers in flight (2 latency exposures).
// xq broadcasts folded into compute (L2-resident). Cross-wave LDS combine
// cuts atomics 4x vs round 8: 128 lane-atomics/block.
__global__ __launch_bounds__(256) void k_stats64(const int* __restrict__ idx,
    const ushort_t* __restrict__ xqh, const ushort_t* __restrict__ xkh,
    const float* __restrict__ pr1, const float* __restrict__ f3,
    const float* __restrict__ Wp2, const float* __restrict__ bp2,
    float* __restrict__ ws)
{
  __shared__ float lds[4][64];
  int lane = threadIdx.x & 63;
  int r16 = lane & 15, g = lane >> 4;
  int wv = threadIdx.x >> 6;
  int uid = __builtin_amdgcn_readfirstlane(blockIdx.x*4 + wv);
  int half = uid & 1;                // == wv & 1 (blockIdx*4 is even)
  int t0 = (uid >> 1) * 8;           // 8 tiles per wave-unit
  int hoff = half * 32;

  // phase A: per-lane idx + pr1 rows (all independent, issue together)
  int ivv[8];
#pragma unroll
  for (int t = 0; t < 8; t++) ivv[t] = idx[(t0+t)*16 + r16];
  float pa[8], pb[8], pc[8];
#pragma unroll
  for (int t = 0; t < 8; t++){
    int r = (t0+t)*16 + r16;
    pa[t] = pr1[(size_t)r*3+0];
    pb[t] = pr1[(size_t)r*3+1];
    pc[t] = pr1[(size_t)r*3+2];
  }
  // phase B: all 8 gathers in flight
  bf16x8 kk[8];
#pragma unroll
  for (int t = 0; t < 8; t++)
    kk[t] = *(const bf16x8*)(xkh + (size_t)ivv[t]*CH + hoff + g*8);

  // per-lane channel constants
  float sc0=f3[0], sc1=f3[1], sc2=f3[2], sh0=f3[3], sh1=f3[4], sh2=f3[5];
  float wpa[8], wpb[8], wpc[8], bpv[8];
#pragma unroll
  for (int j = 0; j < 8; j++){
    int c = hoff + g*8 + j;
    wpa[j] = Wp2[c*3+0]; wpb[j] = Wp2[c*3+1]; wpc[j] = Wp2[c*3+2];
    bpv[j] = bp2[c];
  }

  float accs[8], accq[8];
#pragma unroll
  for (int j = 0; j < 8; j++){ accs[j]=0.f; accq[j]=0.f; }

#pragma unroll
  for (int t = 0; t < 8; t++){
    bf16x8 qq = *(const bf16x8*)(xqh + (size_t)(t0+t)*CH + hoff + g*8);
    float rb0 = fmaxf(fmaf(pa[t], sc0, sh0), 0.f);
    float rb1 = fmaxf(fmaf(pb[t], sc1, sh1), 0.f);
    float rb2 = fmaxf(fmaf(pc[t], sc2, sh2), 0.f);
#pragma unroll
    for (int j = 0; j < 8; j++){
      float w = bf2f((ushort_t)kk[t][j]) - bf2f((ushort_t)qq[j])
              + bpv[j] + rb0*wpa[j] + rb1*wpb[j] + rb2*wpc[j];
      accs[j] += w; accq[j] = fmaf(w, w, accq[j]);
    }
  }

  // reduce over r16 (lane bits 0..3)
#pragma unroll
  for (int j = 0; j < 8; j++){
#pragma unroll
    for (int m = 1; m <= 8; m <<= 1){
      accs[j] += __shfl_xor(accs[j], m);
      accq[j] += __shfl_xor(accq[j], m);
    }
  }
  // per-wave partials -> LDS (lanes r16==0: g=0..3 each hold 8 channels)
  if (r16 == 0){
#pragma unroll
    for (int j = 0; j < 8; j++){
      lds[wv][g*8 + j]      = accs[j];
      lds[wv][32 + g*8 + j] = accq[j];
    }
  }
  __syncthreads();
  // combine waves sharing the same half (wv0&2 -> half0, wv1&3 -> half1)
  int t = threadIdx.x;
  if (t < 128){
    int h = t >> 6;          // 0: half0, 1: half1
    int u = t & 63;          // 0..31 sums, 32..63 sqs
    float v = lds[h][u] + lds[h+2][u];
    float* bank = ws + (blockIdx.x & (BANKS-1))*BANK_STRIDE;
    int c = h*32 + (u & 31);
    atomicAdd(bank + ((u < 32) ? (BOFF_S64S + c) : (BOFF_S64Q + c)), v);
  }
}

// w2 = relu(bn64(w_pre)) @ Ww1^T + bw1 via MFMA. Wave per 16 tiles.
// A-frag: lane holds rb[row r16][ch g*8+j] (chunk0) / +32 (chunk1).
// B-frag: lane holds Ww1[o=(r16&7)][same ch]. D: col=r16 (o), row=g*4+reg.
__global__ __launch_bounds__(256) void k_w2(const int* __restrict__ idx,
    const ushort_t* __restrict__ xqh, const ushort_t* __restrict__ xkh,
    const float* __restrict__ pr1, const float* __restrict__ f3,
    const float* __restrict__ f64, const float* __restrict__ Wp2,
    const float* __restrict__ bp2, const float* __restrict__ Ww1,
    const float* __restrict__ bw1, float* __restrict__ w2o,
    float* __restrict__ ws)
{
  int lane = threadIdx.x & 63;
  int r16 = lane & 15, g = lane >> 4;
  int oc = r16 & 7;
  int t0 = __builtin_amdgcn_readfirstlane((blockIdx.x*4 + (threadIdx.x >> 6)) * 16);

  float sc30=f3[0], sc31=f3[1], sc32=f3[2], sh30=f3[3], sh31=f3[4], sh32=f3[5];
  float wpaL[8],wpbL[8],wpcL[8],bpL[8],bscL[8],bshL[8];
  float wpaH[8],wpbH[8],wpcH[8],bpH[8],bscH[8],bshH[8];
#pragma unroll
  for (int j = 0; j < 8; j++){
    int cL = g*8 + j, cH = cL + 32;
    wpaL[j]=Wp2[cL*3+0]; wpbL[j]=Wp2[cL*3+1]; wpcL[j]=Wp2[cL*3+2];
    bpL[j]=bp2[cL]; bscL[j]=f64[cL]; bshL[j]=f64[64+cL];
    wpaH[j]=Wp2[cH*3+0]; wpbH[j]=Wp2[cH*3+1]; wpcH[j]=Wp2[cH*3+2];
    bpH[j]=bp2[cH]; bscH[j]=f64[cH]; bshH[j]=f64[64+cH];
  }
  bf16x8 bf0, bf1;
#pragma unroll
  for (int j = 0; j < 8; j++){
    bf0[j] = (short)f2bf(Ww1[oc*CH + g*8 + j]);
    bf1[j] = (short)f2bf(Ww1[oc*CH + 32 + g*8 + j]);
  }
  float bwv = bw1[oc];

  float SB = 0.f, SQ = 0.f;

  int tile = t0;
  int iv   = idx[tile*16 + r16];
  float a0 = pr1[(size_t)(tile*16+r16)*3+0];
  float a1 = pr1[(size_t)(tile*16+r16)*3+1];
  float a2 = pr1[(size_t)(tile*16+r16)*3+2];

#pragma unroll 1
  for (int t = 0; t < 16; t++){
    bf16x8 k0 = *(const bf16x8*)(xkh + (size_t)iv*CH + g*8);
    bf16x8 k1 = *(const bf16x8*)(xkh + (size_t)iv*CH + 32 + g*8);
    bf16x8 q0 = *(const bf16x8*)(xqh + (size_t)tile*CH + g*8);
    bf16x8 q1 = *(const bf16x8*)(xqh + (size_t)tile*CH + 32 + g*8);
    int ivn = 0; float c0=0.f, c1=0.f, c2=0.f;
    if (t < 15){
      int rn = (tile+1)*16 + r16;
      ivn = idx[rn];
      c0 = pr1[(size_t)rn*3+0]; c1 = pr1[(size_t)rn*3+1]; c2 = pr1[(size_t)rn*3+2];
    }
    float rb0 = fmaxf(fmaf(a0, sc30, sh30), 0.f);
    float rb1 = fmaxf(fmaf(a1, sc31, sh31), 0.f);
    float rb2 = fmaxf(fmaf(a2, sc32, sh32), 0.f);
    bf16x8 af0, af1;
#pragma unroll
    for (int j = 0; j < 8; j++){
      float pr2L = bpL[j] + rb0*wpaL[j] + rb1*wpbL[j] + rb2*wpcL[j];
      float wL = bf2f((ushort_t)k0[j]) - bf2f((ushort_t)q0[j]) + pr2L;
      af0[j] = (short)f2bf(fmaxf(fmaf(wL, bscL[j], bshL[j]), 0.f));
      float pr2H = bpH[j] + rb0*wpaH[j] + rb1*wpbH[j] + rb2*wpcH[j];
      float wH = bf2f((ushort_t)k1[j]) - bf2f((ushort_t)q1[j]) + pr2H;
      af1[j] = (short)f2bf(fmaxf(fmaf(wH, bscH[j], bshH[j]), 0.f));
    }
    f32x4 d = {0.f, 0.f, 0.f, 0.f};
    d = __builtin_amdgcn_mfma_f32_16x16x32_bf16(af0, bf0, d, 0, 0, 0);
    d = __builtin_amdgcn_mfma_f32_16x16x32_bf16(af1, bf1, d, 0, 0, 0);
    int row0 = tile*16;
    float dv0 = d[0]+bwv, dv1 = d[1]+bwv, dv2 = d[2]+bwv, dv3 = d[3]+bwv;
    if (r16 < 8){
      w2o[(size_t)(row0 + g*4 + 0)*8 + r16] = dv0;
      w2o[(size_t)(row0 + g*4 + 1)*8 + r16] = dv1;
      w2o[(size_t)(row0 + g*4 + 2)*8 + r16] = dv2;
      w2o[(size_t)(row0 + g*4 + 3)*8 + r16] = dv3;
    }
    SB += dv0+dv1+dv2+dv3;
    SQ += dv0*dv0 + dv1*dv1 + dv2*dv2 + dv3*dv3;
    tile++; iv = ivn; a0 = c0; a1 = c1; a2 = c2;
  }
  SB += __shfl_xor(SB, 16); SB += __shfl_xor(SB, 32);
  SQ += __shfl_xor(SQ, 16); SQ += __shfl_xor(SQ, 32);
  if (lane < 8){
    float* bank = ws + (blockIdx.x & (BANKS-1))*BANK_STRIDE;
    atomicAdd(bank + BOFF_S8S + lane, SB);
    atomicAdd(bank + BOFF_S8Q + lane, SQ);
  }
}

// final: w3 = relu(bn8(w2)) @ Ww2^T + bw2 ; softmax over 16 neighbors ;
// out = sum_j (xv+p_r2)*w. (round-4 form: uniform loads, no LDS in loop)
__global__ __launch_bounds__(256) void k_out(const int* __restrict__ idx,
    const ushort_t* __restrict__ xvh, const float* __restrict__ pr1,
    const float* __restrict__ w2, const float* __restrict__ f3,
    const float* __restrict__ f8, const float* __restrict__ Wp2,
    const float* __restrict__ bp2, const float* __restrict__ Ww2,
    const float* __restrict__ bw2, float* __restrict__ out)
{
  int lane = threadIdx.x & 63, wv = threadIdx.x >> 6;
  int n = __builtin_amdgcn_readfirstlane(blockIdx.x*4 + wv);
  int cp = lane & 7;
  int jg = lane >> 3;

  int iv[16]; float a0[16], a1[16], a2[16];
#pragma unroll
  for (int j = 0; j < 16; j++){
    int r = n*NSAMP + j;
    iv[j] = idx[r];
    a0[j] = pr1[(size_t)r*3+0];
    a1[j] = pr1[(size_t)r*3+1];
    a2[j] = pr1[(size_t)r*3+2];
  }
  ushort_t xvv[16];
#pragma unroll
  for (int j = 0; j < 16; j++) xvv[j] = xvh[(size_t)iv[j]*CH + lane];

  float wpa = Wp2[lane*3+0], wpb = Wp2[lane*3+1], wpc = Wp2[lane*3+2];
  float bp  = bp2[lane];
  float ww2_[8];
#pragma unroll
  for (int k = 0; k < 8; k++) ww2_[k] = Ww2[cp*8 + k];
  float bw = bw2[cp];
  float sc8[8], sh8[8];
#pragma unroll
  for (int k = 0; k < 8; k++){ sc8[k]=f8[k]; sh8[k]=f8[8+k]; }
  float sc30=f3[0], sc31=f3[1], sc32=f3[2], sh30=f3[3], sh31=f3[4], sh32=f3[5];

  const float4* ra  = (const float4*)(w2 + ((size_t)n*NSAMP + jg)*8);
  const float4* rbp = (const float4*)(w2 + ((size_t)n*NSAMP + jg + 8)*8);
  float4 A0 = ra[0],  A1 = ra[1];
  float4 B0 = rbp[0], B1 = rbp[1];
  float w3a = bw, w3b = bw;
#pragma unroll
  for (int k = 0; k < 8; k++){
    float va = (k < 4) ? ((k==0)?A0.x:(k==1)?A0.y:(k==2)?A0.z:A0.w)
                       : ((k==4)?A1.x:(k==5)?A1.y:(k==6)?A1.z:A1.w);
    float vb = (k < 4) ? ((k==0)?B0.x:(k==1)?B0.y:(k==2)?B0.z:B0.w)
                       : ((k==4)?B1.x:(k==5)?B1.y:(k==6)?B1.z:B1.w);
    float rba = fmaxf(va*sc8[k]+sh8[k], 0.0f);
    float rbb = fmaxf(vb*sc8[k]+sh8[k], 0.0f);
    w3a += rba * ww2_[k];
    w3b += rbb * ww2_[k];
  }

  float m = fmaxf(w3a, w3b);
#pragma unroll
  for (int mask = 8; mask <= 32; mask <<= 1) m = fmaxf(m, __shfl_xor(m, mask));
  float ea = expf(w3a - m), eb = expf(w3b - m);
  float ssum = ea + eb;
#pragma unroll
  for (int mask = 8; mask <= 32; mask <<= 1) ssum += __shfl_xor(ssum, mask);
  float inv = 1.0f / ssum;
  ea *= inv; eb *= inv;

  float oacc = 0.0f;
#pragma unroll
  for (int j = 0; j < NSAMP; j++){
    float wn = __shfl(j < 8 ? ea : eb, ((j & 7) << 3) | cp);
    float rb0 = fmaxf(fmaf(a0[j], sc30, sh30), 0.0f);
    float rb1 = fmaxf(fmaf(a1[j], sc31, sh31), 0.0f);
    float rb2 = fmaxf(fmaf(a2[j], sc32, sh32), 0.0f);
    float pr2v = bp + rb0*wpa + rb1*wpb + rb2*wpc;
    oacc += (bf2f(xvv[j]) + pr2v) * wn;
  }
  out[(size_t)n*CH + lane] = oacc;
}

extern "C" void kernel_launch(void* const* d_in, const int* in_sizes, int n_in,
                              void* d_out, int out_size, void* d_ws, size_t ws_size,
                              hipStream_t stream)
{
  const float* p    = (const float*)d_in[0];
  const float* x    = (const float*)d_in[1];
  const int*   idx  = (const int*)d_in[2];
  const float* Wq   = (const float*)d_in[3];
  const float* bq   = (const float*)d_in[4];
  const float* Wk   = (const float*)d_in[5];
  const float* bk   = (const float*)d_in[6];
  const float* Wv   = (const float*)d_in[7];
  const float* bv   = (const float*)d_in[8];
  const float* Wp1  = (const float*)d_in[9];
  const float* bp1  = (const float*)d_in[10];
  const float* gp   = (const float*)d_in[11];
  const float* betap= (const float*)d_in[12];
  const float* Wp2  = (const float*)d_in[13];
  const float* bp2  = (const float*)d_in[14];
  const float* gw1  = (const float*)d_in[15];
  const float* betaw1=(const float*)d_in[16];
  const float* Ww1  = (const float*)d_in[17];
  const float* bw1  = (const float*)d_in[18];
  const float* gw2  = (const float*)d_in[19];
  const float* betaw2=(const float*)d_in[20];
  const float* Ww2  = (const float*)d_in[21];
  const float* bw2  = (const float*)d_in[22];
  float* ws  = (float*)d_ws;
  float* out = (float*)d_out;

  ushort_t* xqh = (ushort_t*)(ws + OFF_XQH);
  ushort_t* xkh = (ushort_t*)(ws + OFF_XKH);
  ushort_t* xvh = (ushort_t*)(ws + OFF_XVH);

  k_zero<<<dim3(1), dim3(256), 0, stream>>>(ws);
  k_proj<<<dim3(NPTS/256, 3), dim3(256), 0, stream>>>(x, Wq,bq, Wk,bk, Wv,bv,
      xqh, xkh, xvh);
  k_pr1<<<dim3(1024), dim3(256), 0, stream>>>(p, idx, Wp1, bp1, ws);
  k_finalize<<<dim3(1), dim3(64), 0, stream>>>(ws, ws+OFF_F3, gp, betap,
      3, BOFF_S3S, BOFF_S3S+3);
  k_stats64<<<dim3(4096), dim3(256), 0, stream>>>(idx, xqh, xkh,
      ws+OFF_PR1, ws+OFF_F3, Wp2, bp2, ws);
  k_finalize<<<dim3(1), dim3(64), 0, stream>>>(ws, ws+OFF_F64, gw1, betaw1,
      64, BOFF_S64S, BOFF_S64Q);
  k_w2<<<dim3(1024), dim3(256), 0, stream>>>(idx, xqh, xkh, ws+OFF_PR1,
      ws+OFF_F3, ws+OFF_F64, Wp2, bp2, Ww1, bw1, ws+OFF_W2, ws);
  k_finalize<<<dim3(1), dim3(64), 0, stream>>>(ws, ws+OFF_F8, gw2, betaw2,
      8, BOFF_S8S, BOFF_S8Q);
  k_out<<<dim3(NPTS/4), dim3(256), 0, stream>>>(idx, xvh, ws+OFF_PR1, ws+OFF_W2,
      ws+OFF_F3, ws+OFF_F8, Wp2, bp2, Ww2, bw2, out);
}